// Round 18
// baseline (862.382 us; speedup 1.0000x reference)
//
#include <hip/hip_runtime.h>
#include <hip/hip_bf16.h>
#include <stdint.h>

// MoE FFN: sigmoid router (group-limited greedy top-8 of 64), SwiGLU experts
// (1024->512->1024) + shared expert (1024->2048->1024). All inputs fp32.
// R21: R20 base (best, 826.9us) + two low-risk catalog levers:
// (a) T5 s_setprio(1) around MFMA clusters in both GEMMs (reg-staged B gives
// wave role diversity -> setprio's measured-positive regime, m191 +4-7%);
// (b) T1 chunked XCD swizzle on fused_all work mapping ((bid&7)*448+(bid>>3),
// 3584=8x448 bijective): the 8 n-sibling blocks sharing one gathered A-panel
// land on ONE XCD -> panel becomes L2-hit (latency-bound kernel).
// down_all keeps heavy-first order (no swizzle). Everything else R20-exact:
// fp32-direct weights, R18 B-staging (16 scalar loads, bwr XOR layout,
// vmcnt(16/18/0)), fused router chain, unified grids, worklist, combine.

#define S_TOK 4096
#define C_DIM 1024
#define E_NUM 64
#define H_DIM 512
#define HS_DIM 2048
#define ROWS_TOTAL (S_TOK * 8)
#define T_TILES 320
#define NB_ROUTED_F (T_TILES * 8)     // 2560 fused routed blocks
#define NB_SHARED_F (32 * 32)         // 1024 fused shared blocks
#define NB_FUSED_ALL (NB_ROUTED_F + NB_SHARED_F)   // 3584 = 8 * 448
#define NB_ROUTED_D (T_TILES * 8)     // 2560 down routed blocks
#define NB_SHARED_D (32 * 8)          // 256 down shared blocks (heavy, first)

typedef __attribute__((ext_vector_type(8))) short short8;
typedef __attribute__((ext_vector_type(4))) float f32x4;
typedef __attribute__((ext_vector_type(2))) unsigned int uint2v;

static __device__ __forceinline__ unsigned short f2bf(float f) {
    union { float f; uint32_t u; } v; v.f = f;
    uint32_t u = v.u;
    u += 0x7fffu + ((u >> 16) & 1u);   // RNE
    return (unsigned short)(u >> 16);
}

static __device__ __forceinline__ uint32_t cvtpk(float a, float b) {
    uint32_t r;
    asm("v_cvt_pk_bf16_f32 %0, %1, %2" : "=v"(r) : "v"(a), "v"(b));
    return r;
}

static __device__ __forceinline__ void gl2lds16(const void* g, void* l) {
    __builtin_amdgcn_global_load_lds(
        (const __attribute__((address_space(1))) uint32_t*)g,
        (__attribute__((address_space(3))) uint32_t*)l, 16, 0, 0);
}

// ---- router + topk + scan + scatter + x-cvt, ONE kernel, 128 blocks ----
__global__ __launch_bounds__(256)
void router_all_k(const float* __restrict__ x, const float* __restrict__ rw,
                  const float* __restrict__ ebias,
                  int* __restrict__ topk_idx, float* __restrict__ topk_w,
                  int* __restrict__ counts, int* __restrict__ done, int* __restrict__ flag,
                  int* __restrict__ base, int* __restrict__ cursor,
                  int* __restrict__ tile_e, int* __restrict__ tile_m0,
                  int* __restrict__ row_token, float* __restrict__ row_wgt,
                  int* __restrict__ pos_of, unsigned short* __restrict__ xb) {
    int t0 = blockIdx.x * 32;
    __shared__ float xs[32][36];
    __shared__ float wsm[64][36];
    __shared__ float scf[32][64];
    __shared__ int last_blk;
    int t = threadIdx.x;
    int tx = t & 15, ty = t >> 4;
    float acc[2][4] = {};
    for (int k0 = 0; k0 < C_DIM; k0 += 32) {
        {
            int r = t >> 3, c = t & 7;
            *(float4*)&xs[r][c * 4] = *(const float4*)(x + (size_t)(t0 + r) * C_DIM + k0 + c * 4);
        }
        #pragma unroll
        for (int i = 0; i < 2; i++) {
            int idx = t + 256 * i;
            int r = idx >> 3, c = idx & 7;
            *(float4*)&wsm[r][c * 4] = *(const float4*)(rw + (size_t)r * C_DIM + k0 + c * 4);
        }
        __syncthreads();
        #pragma unroll
        for (int kk = 0; kk < 32; kk += 4) {
            float4 a0 = *(const float4*)&xs[ty * 2 + 0][kk];
            float4 a1 = *(const float4*)&xs[ty * 2 + 1][kk];
            #pragma unroll
            for (int j = 0; j < 4; j++) {
                float4 b = *(const float4*)&wsm[tx * 4 + j][kk];
                acc[0][j] += a0.x * b.x + a0.y * b.y + a0.z * b.z + a0.w * b.w;
                acc[1][j] += a1.x * b.x + a1.y * b.y + a1.z * b.z + a1.w * b.w;
            }
        }
        __syncthreads();
    }
    #pragma unroll
    for (int i = 0; i < 2; i++)
        #pragma unroll
        for (int j = 0; j < 4; j++)
            scf[ty * 2 + i][tx * 4 + j] = 1.f / (1.f + __expf(-acc[i][j]));
    __syncthreads();

    int lane = t & 63, w = t >> 6;
    float eb = ebias[lane];
    for (int r = 0; r < 8; r++) {
        int lt = w * 8 + r;
        int tok = t0 + lt;
        float sc = scf[lt][lane];
        float sb = sc + eb;
        float m1 = sb, m2 = -1e30f;
        #pragma unroll
        for (int off = 1; off <= 4; off <<= 1) {
            float o1 = __shfl_xor(m1, off);
            float o2 = __shfl_xor(m2, off);
            float hi = fmaxf(m1, o1), lo = fminf(m1, o1);
            m2 = fmaxf(lo, fmaxf(m2, o2));
            m1 = hi;
        }
        float grp = m1 + m2;
        float grpv[8];
        #pragma unroll
        for (int g = 0; g < 8; g++) grpv[g] = __shfl(grp, g * 8);
        unsigned gsel = 0;
        #pragma unroll
        for (int k = 0; k < 4; k++) {
            float best = -1e30f; int bi = 0;
            #pragma unroll
            for (int g = 0; g < 8; g++)
                if (!((gsel >> g) & 1) && grpv[g] > best) { best = grpv[g]; bi = g; }
            gsel |= 1u << bi;
        }
        float val = ((gsel >> (lane >> 3)) & 1) ? sb : -1e30f;
        int idx[8]; float sv[8]; float wsum = 0.f;
        #pragma unroll
        for (int k = 0; k < 8; k++) {
            uint32_t u = __float_as_uint(val);
            uint32_t mu = (u & 0x80000000u) ? ~u : (u | 0x80000000u);
            unsigned long long key = ((unsigned long long)mu << 6) | (unsigned long long)(63 - lane);
            #pragma unroll
            for (int off = 32; off; off >>= 1) {
                unsigned long long ok = __shfl_xor(key, off);
                if (ok > key) key = ok;
            }
            int win = 63 - (int)(key & 63ull);
            idx[k] = win;
            sv[k] = __shfl(sc, win);
            wsum += sv[k];
            if (lane == win) val = -1e30f;
        }
        float inv = 1.f / (wsum + 1e-20f);
        if (lane < 8) {
            topk_idx[tok * 8 + lane] = idx[lane];
            topk_w[tok * 8 + lane] = sv[lane] * inv;
            atomicAdd(&counts[idx[lane]], 1);
        }
    }

    __threadfence();
    __syncthreads();
    if (t == 0) last_blk = (atomicAdd(done, 1) == (int)gridDim.x - 1) ? 1 : 0;
    __syncthreads();

    if (last_blk) {
        if (t < 64) {
            int e = t;
            int c = atomicAdd(&counts[e], 0);
            int s = c;
            #pragma unroll
            for (int off = 1; off < 64; off <<= 1) {
                int o = __shfl_up(s, off);
                if (e >= off) s += o;
            }
            int ex = s - c;
            base[e] = ex;
            cursor[e] = ex;
            int nt = (c + 127) >> 7;
            int ts = nt;
            #pragma unroll
            for (int off = 1; off < 64; off <<= 1) {
                int o = __shfl_up(ts, off);
                if (e >= off) ts += o;
            }
            int tb = ts - nt;
            for (int i = 0; i < nt; i++) { tile_e[tb + i] = e; tile_m0[tb + i] = i * 128; }
            int total = __shfl(ts, 63);
            for (int j = total + e; j < T_TILES; j += 64) tile_e[j] = -1;
        }
        __syncthreads();
        __threadfence();
        if (t == 0) atomicExch(flag, 1);
    }

    // x-cvt of this block's 32 token rows (overlaps other blocks' scan wait)
    #pragma unroll
    for (int it = 0; it < 8; it++) {
        int g = t0 * 64 + it * 256 + t;     // unit = 16 floats
        float4 v0 = ((const float4*)x)[4 * g];
        float4 v1 = ((const float4*)x)[4 * g + 1];
        float4 v2 = ((const float4*)x)[4 * g + 2];
        float4 v3 = ((const float4*)x)[4 * g + 3];
        uint32_t pk[8];
        pk[0] = cvtpk(v0.x, v0.y); pk[1] = cvtpk(v0.z, v0.w);
        pk[2] = cvtpk(v1.x, v1.y); pk[3] = cvtpk(v1.z, v1.w);
        pk[4] = cvtpk(v2.x, v2.y); pk[5] = cvtpk(v2.z, v2.w);
        pk[6] = cvtpk(v3.x, v3.y); pk[7] = cvtpk(v3.z, v3.w);
        ((uint4*)xb)[2 * g]     = *(uint4*)&pk[0];
        ((uint4*)xb)[2 * g + 1] = *(uint4*)&pk[4];
    }

    if (t == 0) {
        while (atomicAdd(flag, 0) == 0) __builtin_amdgcn_s_sleep(2);
    }
    __syncthreads();

    {
        int i = t0 * 8 + t;
        int e = topk_idx[i];
        int pos = atomicAdd(&cursor[e], 1);
        row_token[pos] = i >> 3;
        row_wgt[pos] = topk_w[i];
        pos_of[i] = pos;
    }
}

// ---------------- combine: out[t] += sum_k O[pos_of[t*8+k]] ----------------
__global__ __launch_bounds__(256)
void combine_k(const float* __restrict__ O, const int* __restrict__ pos_of,
               float* __restrict__ out) {
    int t = blockIdx.x;
    int c = threadIdx.x;
    float4 s = ((const float4*)(out + (size_t)t * C_DIM))[c];
    int p[8];
    #pragma unroll
    for (int k = 0; k < 8; k++) p[k] = pos_of[t * 8 + k];
    #pragma unroll
    for (int k = 0; k < 8; k++) {
        float4 v = ((const float4*)(O + (size_t)p[k] * C_DIM))[c];
        s.x += v.x; s.y += v.y; s.z += v.z; s.w += v.w;
    }
    ((float4*)(out + (size_t)t * C_DIM))[c] = s;
}

// ---------------- unified FUSED gate+up GEMM: fp32-direct B (R18-exact) ---------
// + chunked XCD swizzle (work = (bid&7)*448 + bid>>3) + setprio around MFMA.
__global__ __launch_bounds__(256, 3)
void fused_all_k(const short* __restrict__ xb,
                 const float* __restrict__ gate_w, const float* __restrict__ up_w,
                 const float* __restrict__ shg_w, const float* __restrict__ shu_w,
                 unsigned short* __restrict__ Hr, unsigned short* __restrict__ Hs,
                 const int* __restrict__ counts, const int* __restrict__ base,
                 const int* __restrict__ row_token,
                 const int* __restrict__ tile_e, const int* __restrict__ tile_m0) {
    constexpr int K = C_DIM;

    // chunked XCD swizzle: 8 n-sibling blocks (same A-panel) -> same XCD
    int bid = (blockIdx.x & 7) * (NB_FUSED_ALL / 8) + (blockIdx.x >> 3);
    bool routed = bid < NB_ROUTED_F;
    const float* B1; const float* B2; unsigned short* Cout;
    int m0, n0, Mrows, rowbase, N;
    if (routed) {
        int ti = bid >> 3;
        int e = tile_e[ti];
        if (e < 0) return;
        m0 = tile_m0[ti]; n0 = (bid & 7) * 64;
        Mrows = counts[e]; rowbase = base[e];
        N = H_DIM;
        B1 = gate_w + (size_t)e * K * H_DIM;
        B2 = up_w   + (size_t)e * K * H_DIM;
        Cout = Hr;
    } else {
        int s = bid - NB_ROUTED_F;
        m0 = (s >> 5) * 128; n0 = (s & 31) * 64;
        Mrows = S_TOK; rowbase = 0;
        N = HS_DIM;
        B1 = shg_w; B2 = shu_w;
        Cout = Hs;
    }

    __shared__ short As[3 * 4096];        // 24 KB
    __shared__ short Bs1[2 * 2048];       // 8 KB
    __shared__ short Bs2[2 * 2048];       // 8 KB -> 40 KB, 3 blocks/CU

    int tid = threadIdx.x;
    int lane = tid & 63, w = tid >> 6;
    int wr = w >> 1, wc = w & 1;
    int quad = lane >> 4, l16 = lane & 15;
    int sr = lane >> 2, sc = lane & 3;

    const short* aptr[2];
    #pragma unroll
    for (int i = 0; i < 2; i++) {
        int row = w * 32 + i * 16 + sr;
        int mrow = m0 + row;
        int cl = mrow < Mrows ? mrow : (Mrows - 1);
        size_t arow = routed ? (size_t)row_token[rowbase + cl] : (size_t)cl;
        aptr[i] = xb + arow * K + sc * 8;
    }

    int nb = tid & 63, kg = tid >> 6;
    const float* b1g = B1 + (size_t)(kg * 8) * N + n0 + nb;
    const float* b2g = B2 + (size_t)(kg * 8) * N + n0 + nb;
    const int bwr = nb * 32 + ((kg * 8) ^ ((nb & 3) << 3));

    f32x4 acc1[4][2] = {};
    f32x4 acc2[4][2] = {};

    const int nk = K >> 5;                 // 32
    auto stageA = [&](int slot) {
        #pragma unroll
        for (int i = 0; i < 2; i++) {
            gl2lds16(aptr[i], &As[slot * 4096 + (w * 32 + i * 16) * 32]);
            aptr[i] += 32;
        }
    };
    auto loadB = [&](float (&fb)[2][8]) {
        #pragma unroll
        for (int jj = 0; jj < 8; jj++) fb[0][jj] = b1g[(size_t)jj * N];
        #pragma unroll
        for (int jj = 0; jj < 8; jj++) fb[1][jj] = b2g[(size_t)jj * N];
        b1g += (size_t)32 * N;
        b2g += (size_t)32 * N;
    };
    auto writeB = [&](int buf, float (&fb)[2][8]) {
        uint32_t w0[4], w1[4];
        #pragma unroll
        for (int q = 0; q < 4; q++) {
            w0[q] = cvtpk(fb[0][2 * q], fb[0][2 * q + 1]);
            w1[q] = cvtpk(fb[1][2 * q], fb[1][2 * q + 1]);
        }
        *(uint4*)&Bs1[buf * 2048 + bwr] = *(uint4*)w0;
        *(uint4*)&Bs2[buf * 2048 + bwr] = *(uint4*)w1;
    };

    float fbA[2][8], fbB[2][8];
    stageA(0);
    stageA(1);
    __builtin_amdgcn_sched_barrier(0);
    {
        float fb0[2][8];
        loadB(fb0);
        writeB(0, fb0);                    // implicit wait drains fb0 (+A0,A1)
    }
    __builtin_amdgcn_sched_barrier(0);
    loadB(fbA);                            // tile 1, left in flight
    asm volatile("s_waitcnt vmcnt(16) lgkmcnt(0)" ::: "memory");
    __builtin_amdgcn_s_barrier();
    __builtin_amdgcn_sched_barrier(0);

    auto kstep = [&](int t, float (&fbIn)[2][8], float (&fbOut)[2][8]) {
        int slot = t % 3;
        int bbuf = t & 1;
        bool pf = (t + 2 < nk);
        if (pf) { stageA((t + 2) % 3); loadB(fbOut); }

        short8 a[4], b1[2], b2[2];
        #pragma unroll
        for (int i = 0; i < 4; i++)
            a[i] = *(const short8*)&As[slot * 4096 + (wr * 64 + i * 16 + l16) * 32 + quad * 8];
        #pragma unroll
        for (int j = 0; j < 2; j++) {
            int row = wc * 32 + j * 16 + l16;
            int ro = row * 32 + ((quad * 8) ^ ((row & 3) << 3));
            b1[j] = *(const short8*)&Bs1[bbuf * 2048 + ro];
            b2[j] = *(const short8*)&Bs2[bbuf * 2048 + ro];
        }
        __builtin_amdgcn_s_setprio(1);
        #pragma unroll
        for (int i = 0; i < 4; i++)
            #pragma unroll
            for (int j = 0; j < 2; j++) {
                acc1[i][j] = __builtin_amdgcn_mfma_f32_16x16x32_bf16(a[i], b1[j], acc1[i][j], 0, 0, 0);
                acc2[i][j] = __builtin_amdgcn_mfma_f32_16x16x32_bf16(a[i], b2[j], acc2[i][j], 0, 0, 0);
            }
        __builtin_amdgcn_s_setprio(0);
        if (t + 1 < nk) {
            writeB((t + 1) & 1, fbIn);     // implicit wait on fbIn (drains A(t+1))
            if (pf) asm volatile("s_waitcnt vmcnt(18) lgkmcnt(0)" ::: "memory");
            else    asm volatile("s_waitcnt vmcnt(0) lgkmcnt(0)" ::: "memory");
            __builtin_amdgcn_s_barrier();
            __builtin_amdgcn_sched_barrier(0);
        }
    };

    for (int t = 0; t < nk; t += 2) {
        kstep(t, fbA, fbB);
        if (t + 1 < nk) kstep(t + 1, fbB, fbA);
    }

    #pragma unroll
    for (int i = 0; i < 4; i++) {
        #pragma unroll
        for (int rr = 0; rr < 4; rr++) {
            int row = m0 + wr * 64 + i * 16 + quad * 4 + rr;
            if (row >= Mrows) continue;
            size_t orow = (size_t)(rowbase + row);
            #pragma unroll
            for (int j = 0; j < 2; j++) {
                int n = n0 + wc * 32 + j * 16 + l16;
                float v = acc1[i][j][rr];
                float u = acc2[i][j][rr];
                float h = v / (1.f + __expf(-v)) * u;
                Cout[orow * N + n] = f2bf(h);
            }
        }
    }
}

// ---------------- unified DOWN GEMM: fp32-direct B (R18-exact), shared-heavy first
__global__ __launch_bounds__(256, 3)
void down_all_k(const short* __restrict__ Hr, const short* __restrict__ Hs,
                const float* __restrict__ down_w, const float* __restrict__ shd_w,
                float* __restrict__ O, float* __restrict__ out,
                const int* __restrict__ counts, const int* __restrict__ base,
                const float* __restrict__ row_wgt,
                const int* __restrict__ tile_e, const int* __restrict__ tile_m0) {
    constexpr int N = C_DIM;

    int bid = blockIdx.x;
    bool shared_e = bid < NB_SHARED_D;     // heavy blocks first (4x work)
    const short* A; const float* B1; float* Cout;
    int m0, n0, Mrows, rowbase, K;
    if (shared_e) {
        m0 = (bid >> 3) * 128; n0 = (bid & 7) * 128;
        Mrows = S_TOK; rowbase = 0;
        K = HS_DIM;
        A = Hs;
        B1 = shd_w;
        Cout = out;
    } else {
        int rb = bid - NB_SHARED_D;
        int ti = rb >> 3;
        int e = tile_e[ti];
        if (e < 0) return;
        m0 = tile_m0[ti]; n0 = (rb & 7) * 128;
        Mrows = counts[e]; rowbase = base[e];
        K = H_DIM;
        A = Hr;
        B1 = down_w + (size_t)e * H_DIM * N;
        Cout = O;
    }

    __shared__ short As[3 * 4096];        // 24 KB
    __shared__ short Bs1[2 * 4096];       // 16 KB -> 40 KB, 3 blocks/CU

    int tid = threadIdx.x;
    int lane = tid & 63, w = tid >> 6;
    int wr = w >> 1, wc = w & 1;
    int quad = lane >> 4, l16 = lane & 15;
    int sr = lane >> 2, sc = lane & 3;

    const short* aptr[2];
    #pragma unroll
    for (int i = 0; i < 2; i++) {
        int row = w * 32 + i * 16 + sr;
        int mrow = m0 + row;
        int cl = mrow < Mrows ? mrow : (Mrows - 1);
        aptr[i] = A + (size_t)(rowbase + cl) * K + sc * 8;
    }

    int nb = tid & 63, kg = tid >> 6;
    const float* b1g = B1 + (size_t)(kg * 8) * N + n0 + nb;
    const int bwr = nb * 32 + ((kg * 8) ^ ((nb & 3) << 3));

    f32x4 acc1[4][4] = {};

    const int nk = K >> 5;                 // 16 or 64
    auto stageA = [&](int slot) {
        #pragma unroll
        for (int i = 0; i < 2; i++) {
            gl2lds16(aptr[i], &As[slot * 4096 + (w * 32 + i * 16) * 32]);
            aptr[i] += 32;
        }
    };
    auto loadB = [&](float (&fb)[2][8]) {
        #pragma unroll
        for (int jj = 0; jj < 8; jj++) fb[0][jj] = b1g[(size_t)jj * N];
        #pragma unroll
        for (int jj = 0; jj < 8; jj++) fb[1][jj] = b1g[(size_t)jj * N + 64];
        b1g += (size_t)32 * N;
    };
    auto writeB = [&](int buf, float (&fb)[2][8]) {
        uint32_t w0[4], w1[4];
        #pragma unroll
        for (int q = 0; q < 4; q++) {
            w0[q] = cvtpk(fb[0][2 * q], fb[0][2 * q + 1]);
            w1[q] = cvtpk(fb[1][2 * q], fb[1][2 * q + 1]);
        }
        *(uint4*)&Bs1[buf * 4096 + bwr] = *(uint4*)w0;
        *(uint4*)&Bs1[buf * 4096 + bwr + 64 * 32] = *(uint4*)w1;
    };

    float fbA[2][8], fbB[2][8];
    stageA(0);
    stageA(1);
    __builtin_amdgcn_sched_barrier(0);
    {
        float fb0[2][8];
        loadB(fb0);
        writeB(0, fb0);
    }
    __builtin_amdgcn_sched_barrier(0);
    loadB(fbA);
    asm volatile("s_waitcnt vmcnt(16) lgkmcnt(0)" ::: "memory");
    __builtin_amdgcn_s_barrier();
    __builtin_amdgcn_sched_barrier(0);

    auto kstep = [&](int t, float (&fbIn)[2][8], float (&fbOut)[2][8]) {
        int slot = t % 3;
        int bbuf = t & 1;
        bool pf = (t + 2 < nk);
        if (pf) { stageA((t + 2) % 3); loadB(fbOut); }

        short8 a[4], b1[4];
        #pragma unroll
        for (int i = 0; i < 4; i++)
            a[i] = *(const short8*)&As[slot * 4096 + (wr * 64 + i * 16 + l16) * 32 + quad * 8];
        #pragma unroll
        for (int j = 0; j < 4; j++) {
            int row = wc * 64 + j * 16 + l16;
            int ro = row * 32 + ((quad * 8) ^ ((row & 3) << 3));
            b1[j] = *(const short8*)&Bs1[bbuf * 4096 + ro];
        }
        __builtin_amdgcn_s_setprio(1);
        #pragma unroll
        for (int i = 0; i < 4; i++)
            #pragma unroll
            for (int j = 0; j < 4; j++)
                acc1[i][j] = __builtin_amdgcn_mfma_f32_16x16x32_bf16(a[i], b1[j], acc1[i][j], 0, 0, 0);
        __builtin_amdgcn_s_setprio(0);
        if (t + 1 < nk) {
            writeB((t + 1) & 1, fbIn);
            if (pf) asm volatile("s_waitcnt vmcnt(18) lgkmcnt(0)" ::: "memory");
            else    asm volatile("s_waitcnt vmcnt(0) lgkmcnt(0)" ::: "memory");
            __builtin_amdgcn_s_barrier();
            __builtin_amdgcn_sched_barrier(0);
        }
    };

    for (int t = 0; t < nk; t += 2) {
        kstep(t, fbA, fbB);
        if (t + 1 < nk) kstep(t + 1, fbB, fbA);
    }

    #pragma unroll
    for (int i = 0; i < 4; i++) {
        #pragma unroll
        for (int rr = 0; rr < 4; rr++) {
            int row = m0 + wr * 64 + i * 16 + quad * 4 + rr;
            if (row >= Mrows) continue;
            size_t orow = (size_t)(rowbase + row);
            float scl = shared_e ? 1.f : row_wgt[rowbase + row];
            #pragma unroll
            for (int j = 0; j < 4; j++) {
                int n = n0 + wc * 64 + j * 16 + l16;
                Cout[orow * N + n] = acc1[i][j][rr] * scl;
            }
        }
    }
}

// ---------------- launch ----------------
extern "C" void kernel_launch(void* const* d_in, const int* in_sizes, int n_in,
                              void* d_out, int out_size, void* d_ws, size_t ws_size,
                              hipStream_t stream) {
    const float* x        = (const float*)d_in[0];
    const float* router_w = (const float*)d_in[1];
    const float* e_bias   = (const float*)d_in[2];
    const float* gate_w   = (const float*)d_in[3];
    const float* up_w     = (const float*)d_in[4];
    const float* down_w   = (const float*)d_in[5];
    const float* sh_gate  = (const float*)d_in[6];
    const float* sh_up    = (const float*)d_in[7];
    const float* sh_down  = (const float*)d_in[8];
    float* out = (float*)d_out;
    char* ws = (char*)d_ws;

    int*   counts    = (int*)(ws);
    int*   base      = (int*)(ws + 256);
    int*   cursor    = (int*)(ws + 512);
    int*   done      = (int*)(ws + 768);
    int*   flag      = (int*)(ws + 772);
    int*   topk_idx  = (int*)(ws + 1024);
    float* topk_w    = (float*)(ws + 1024 + 131072);
    int*   row_token = (int*)(ws + 1024 + 2 * 131072);
    float* row_wgt   = (float*)(ws + 1024 + 3 * 131072);
    int*   pos_of    = (int*)(ws + 1664 * 1024);                   // 128 KB
    int*   tile_e    = (int*)(ws + 1800 * 1024);
    int*   tile_m0   = (int*)(ws + 1808 * 1024);
    const size_t MB = 1u << 20;
    unsigned short* xb = (unsigned short*)(ws + 2 * MB);           // 8 MB
    unsigned short* Hs = (unsigned short*)(ws + 10 * MB);          // 16 MB
    unsigned short* Hr = (unsigned short*)(ws + 26 * MB);          // 32 MB
    float*          O  = (float*)(ws + 70 * MB);                   // 128 MB

    // zero counts/base/cursor/done/flag (graph-capturable)
    hipMemsetAsync(ws, 0, 1024, stream);

    // ---- routing chain: scores + topk + scan + xcvt + scatter, one dispatch ----
    router_all_k<<<S_TOK / 32, 256, 0, stream>>>(
        x, router_w, e_bias, topk_idx, topk_w, counts, done, flag,
        base, cursor, tile_e, tile_m0, row_token, row_wgt, pos_of, xb);

    // ---- unified fused gate+up (routed + shared), fp32-direct weights ----
    fused_all_k<<<NB_FUSED_ALL, 256, 0, stream>>>(
        (const short*)xb, gate_w, up_w, sh_gate, sh_up, Hr, Hs,
        counts, base, row_token, tile_e, tile_m0);

    // ---- unified down (shared heavy first), fp32-direct weights ----
    down_all_k<<<NB_SHARED_D + NB_ROUTED_D, 256, 0, stream>>>(
        (const short*)Hr, (const short*)Hs, down_w, sh_down,
        O, out, counts, base, row_wgt, tile_e, tile_m0);

    // ---- combine routed into out (out already holds shared-expert result) ----
    combine_k<<<S_TOK, 256, 0, stream>>>(O, pos_of, out);
}

// Round 19
// 826.311 us; speedup vs baseline: 1.0437x; 1.0437x over previous
//
#include <hip/hip_runtime.h>
#include <hip/hip_bf16.h>
#include <stdint.h>

// MoE FFN: sigmoid router (group-limited greedy top-8 of 64), SwiGLU experts
// (1024->512->1024) + shared expert (1024->2048->1024). All inputs fp32.
// R22: REVERT to R20-exact (best measured, 826.9us). R21's two levers both
// regressed: XCD swizzle broke B-panel L2 locality (FETCH 325->397MB --
// consecutive worklist tiles of one expert share 4MB of B; my chunking
// scattered them) and setprio+swizzle cost VGPR 72->76 / Occ 30.6->25.9.
// R20 is the measured optimum of every component slot:
// - fp32-direct weights (no cvt prepass; R17 measured cvt at 190us/447MB)
// - R18 B-staging: 16 scalar col-gather loads, cvt_pk, bwr XOR LDS layout,
//   3-slot A-ring + 2-deep B-regs, counted vmcnt(16/18/0)
// - single-dispatch router chain (ticket barrier + overlapped x-cvt/scatter)
// - worklist-balanced routed tiles; unified routed+shared grids; heavy-first
//   down ordering; combine-gather epilogue (no atomics)
// Remaining gap to MFMA floor is the 2-phase 128-tile GEMM structure (m233);
// crossing it needs the 8-phase 256^2 port -- out of budget this session.

#define S_TOK 4096
#define C_DIM 1024
#define E_NUM 64
#define H_DIM 512
#define HS_DIM 2048
#define ROWS_TOTAL (S_TOK * 8)
#define T_TILES 320
#define NB_ROUTED_F (T_TILES * 8)     // 2560 fused routed blocks
#define NB_SHARED_F (32 * 32)         // 1024 fused shared blocks
#define NB_ROUTED_D (T_TILES * 8)     // 2560 down routed blocks
#define NB_SHARED_D (32 * 8)          // 256 down shared blocks (heavy, first)

typedef __attribute__((ext_vector_type(8))) short short8;
typedef __attribute__((ext_vector_type(4))) float f32x4;
typedef __attribute__((ext_vector_type(2))) unsigned int uint2v;

static __device__ __forceinline__ unsigned short f2bf(float f) {
    union { float f; uint32_t u; } v; v.f = f;
    uint32_t u = v.u;
    u += 0x7fffu + ((u >> 16) & 1u);   // RNE
    return (unsigned short)(u >> 16);
}

static __device__ __forceinline__ uint32_t cvtpk(float a, float b) {
    uint32_t r;
    asm("v_cvt_pk_bf16_f32 %0, %1, %2" : "=v"(r) : "v"(a), "v"(b));
    return r;
}

static __device__ __forceinline__ void gl2lds16(const void* g, void* l) {
    __builtin_amdgcn_global_load_lds(
        (const __attribute__((address_space(1))) uint32_t*)g,
        (__attribute__((address_space(3))) uint32_t*)l, 16, 0, 0);
}

// ---- router + topk + scan + scatter + x-cvt, ONE kernel, 128 blocks ----
__global__ __launch_bounds__(256)
void router_all_k(const float* __restrict__ x, const float* __restrict__ rw,
                  const float* __restrict__ ebias,
                  int* __restrict__ topk_idx, float* __restrict__ topk_w,
                  int* __restrict__ counts, int* __restrict__ done, int* __restrict__ flag,
                  int* __restrict__ base, int* __restrict__ cursor,
                  int* __restrict__ tile_e, int* __restrict__ tile_m0,
                  int* __restrict__ row_token, float* __restrict__ row_wgt,
                  int* __restrict__ pos_of, unsigned short* __restrict__ xb) {
    int t0 = blockIdx.x * 32;
    __shared__ float xs[32][36];
    __shared__ float wsm[64][36];
    __shared__ float scf[32][64];
    __shared__ int last_blk;
    int t = threadIdx.x;
    int tx = t & 15, ty = t >> 4;
    float acc[2][4] = {};
    for (int k0 = 0; k0 < C_DIM; k0 += 32) {
        {
            int r = t >> 3, c = t & 7;
            *(float4*)&xs[r][c * 4] = *(const float4*)(x + (size_t)(t0 + r) * C_DIM + k0 + c * 4);
        }
        #pragma unroll
        for (int i = 0; i < 2; i++) {
            int idx = t + 256 * i;
            int r = idx >> 3, c = idx & 7;
            *(float4*)&wsm[r][c * 4] = *(const float4*)(rw + (size_t)r * C_DIM + k0 + c * 4);
        }
        __syncthreads();
        #pragma unroll
        for (int kk = 0; kk < 32; kk += 4) {
            float4 a0 = *(const float4*)&xs[ty * 2 + 0][kk];
            float4 a1 = *(const float4*)&xs[ty * 2 + 1][kk];
            #pragma unroll
            for (int j = 0; j < 4; j++) {
                float4 b = *(const float4*)&wsm[tx * 4 + j][kk];
                acc[0][j] += a0.x * b.x + a0.y * b.y + a0.z * b.z + a0.w * b.w;
                acc[1][j] += a1.x * b.x + a1.y * b.y + a1.z * b.z + a1.w * b.w;
            }
        }
        __syncthreads();
    }
    #pragma unroll
    for (int i = 0; i < 2; i++)
        #pragma unroll
        for (int j = 0; j < 4; j++)
            scf[ty * 2 + i][tx * 4 + j] = 1.f / (1.f + __expf(-acc[i][j]));
    __syncthreads();

    int lane = t & 63, w = t >> 6;
    float eb = ebias[lane];
    for (int r = 0; r < 8; r++) {
        int lt = w * 8 + r;
        int tok = t0 + lt;
        float sc = scf[lt][lane];
        float sb = sc + eb;
        float m1 = sb, m2 = -1e30f;
        #pragma unroll
        for (int off = 1; off <= 4; off <<= 1) {
            float o1 = __shfl_xor(m1, off);
            float o2 = __shfl_xor(m2, off);
            float hi = fmaxf(m1, o1), lo = fminf(m1, o1);
            m2 = fmaxf(lo, fmaxf(m2, o2));
            m1 = hi;
        }
        float grp = m1 + m2;
        float grpv[8];
        #pragma unroll
        for (int g = 0; g < 8; g++) grpv[g] = __shfl(grp, g * 8);
        unsigned gsel = 0;
        #pragma unroll
        for (int k = 0; k < 4; k++) {
            float best = -1e30f; int bi = 0;
            #pragma unroll
            for (int g = 0; g < 8; g++)
                if (!((gsel >> g) & 1) && grpv[g] > best) { best = grpv[g]; bi = g; }
            gsel |= 1u << bi;
        }
        float val = ((gsel >> (lane >> 3)) & 1) ? sb : -1e30f;
        int idx[8]; float sv[8]; float wsum = 0.f;
        #pragma unroll
        for (int k = 0; k < 8; k++) {
            uint32_t u = __float_as_uint(val);
            uint32_t mu = (u & 0x80000000u) ? ~u : (u | 0x80000000u);
            unsigned long long key = ((unsigned long long)mu << 6) | (unsigned long long)(63 - lane);
            #pragma unroll
            for (int off = 32; off; off >>= 1) {
                unsigned long long ok = __shfl_xor(key, off);
                if (ok > key) key = ok;
            }
            int win = 63 - (int)(key & 63ull);
            idx[k] = win;
            sv[k] = __shfl(sc, win);
            wsum += sv[k];
            if (lane == win) val = -1e30f;
        }
        float inv = 1.f / (wsum + 1e-20f);
        if (lane < 8) {
            topk_idx[tok * 8 + lane] = idx[lane];
            topk_w[tok * 8 + lane] = sv[lane] * inv;
            atomicAdd(&counts[idx[lane]], 1);
        }
    }

    __threadfence();
    __syncthreads();
    if (t == 0) last_blk = (atomicAdd(done, 1) == (int)gridDim.x - 1) ? 1 : 0;
    __syncthreads();

    if (last_blk) {
        if (t < 64) {
            int e = t;
            int c = atomicAdd(&counts[e], 0);
            int s = c;
            #pragma unroll
            for (int off = 1; off < 64; off <<= 1) {
                int o = __shfl_up(s, off);
                if (e >= off) s += o;
            }
            int ex = s - c;
            base[e] = ex;
            cursor[e] = ex;
            int nt = (c + 127) >> 7;
            int ts = nt;
            #pragma unroll
            for (int off = 1; off < 64; off <<= 1) {
                int o = __shfl_up(ts, off);
                if (e >= off) ts += o;
            }
            int tb = ts - nt;
            for (int i = 0; i < nt; i++) { tile_e[tb + i] = e; tile_m0[tb + i] = i * 128; }
            int total = __shfl(ts, 63);
            for (int j = total + e; j < T_TILES; j += 64) tile_e[j] = -1;
        }
        __syncthreads();
        __threadfence();
        if (t == 0) atomicExch(flag, 1);
    }

    // x-cvt of this block's 32 token rows (overlaps other blocks' scan wait)
    #pragma unroll
    for (int it = 0; it < 8; it++) {
        int g = t0 * 64 + it * 256 + t;     // unit = 16 floats
        float4 v0 = ((const float4*)x)[4 * g];
        float4 v1 = ((const float4*)x)[4 * g + 1];
        float4 v2 = ((const float4*)x)[4 * g + 2];
        float4 v3 = ((const float4*)x)[4 * g + 3];
        uint32_t pk[8];
        pk[0] = cvtpk(v0.x, v0.y); pk[1] = cvtpk(v0.z, v0.w);
        pk[2] = cvtpk(v1.x, v1.y); pk[3] = cvtpk(v1.z, v1.w);
        pk[4] = cvtpk(v2.x, v2.y); pk[5] = cvtpk(v2.z, v2.w);
        pk[6] = cvtpk(v3.x, v3.y); pk[7] = cvtpk(v3.z, v3.w);
        ((uint4*)xb)[2 * g]     = *(uint4*)&pk[0];
        ((uint4*)xb)[2 * g + 1] = *(uint4*)&pk[4];
    }

    if (t == 0) {
        while (atomicAdd(flag, 0) == 0) __builtin_amdgcn_s_sleep(2);
    }
    __syncthreads();

    {
        int i = t0 * 8 + t;
        int e = topk_idx[i];
        int pos = atomicAdd(&cursor[e], 1);
        row_token[pos] = i >> 3;
        row_wgt[pos] = topk_w[i];
        pos_of[i] = pos;
    }
}

// ---------------- combine: out[t] += sum_k O[pos_of[t*8+k]] ----------------
__global__ __launch_bounds__(256)
void combine_k(const float* __restrict__ O, const int* __restrict__ pos_of,
               float* __restrict__ out) {
    int t = blockIdx.x;
    int c = threadIdx.x;
    float4 s = ((const float4*)(out + (size_t)t * C_DIM))[c];
    int p[8];
    #pragma unroll
    for (int k = 0; k < 8; k++) p[k] = pos_of[t * 8 + k];
    #pragma unroll
    for (int k = 0; k < 8; k++) {
        float4 v = ((const float4*)(O + (size_t)p[k] * C_DIM))[c];
        s.x += v.x; s.y += v.y; s.z += v.z; s.w += v.w;
    }
    ((float4*)(out + (size_t)t * C_DIM))[c] = s;
}

// ---------------- unified FUSED gate+up GEMM: fp32-direct B (R18-exact) ---------
__global__ __launch_bounds__(256, 3)
void fused_all_k(const short* __restrict__ xb,
                 const float* __restrict__ gate_w, const float* __restrict__ up_w,
                 const float* __restrict__ shg_w, const float* __restrict__ shu_w,
                 unsigned short* __restrict__ Hr, unsigned short* __restrict__ Hs,
                 const int* __restrict__ counts, const int* __restrict__ base,
                 const int* __restrict__ row_token,
                 const int* __restrict__ tile_e, const int* __restrict__ tile_m0) {
    constexpr int K = C_DIM;

    int bid = blockIdx.x;
    bool routed = bid < NB_ROUTED_F;
    const float* B1; const float* B2; unsigned short* Cout;
    int m0, n0, Mrows, rowbase, N;
    if (routed) {
        int ti = bid >> 3;
        int e = tile_e[ti];
        if (e < 0) return;
        m0 = tile_m0[ti]; n0 = (bid & 7) * 64;
        Mrows = counts[e]; rowbase = base[e];
        N = H_DIM;
        B1 = gate_w + (size_t)e * K * H_DIM;
        B2 = up_w   + (size_t)e * K * H_DIM;
        Cout = Hr;
    } else {
        int s = bid - NB_ROUTED_F;
        m0 = (s >> 5) * 128; n0 = (s & 31) * 64;
        Mrows = S_TOK; rowbase = 0;
        N = HS_DIM;
        B1 = shg_w; B2 = shu_w;
        Cout = Hs;
    }

    __shared__ short As[3 * 4096];        // 24 KB
    __shared__ short Bs1[2 * 2048];       // 8 KB
    __shared__ short Bs2[2 * 2048];       // 8 KB -> 40 KB, 3 blocks/CU

    int tid = threadIdx.x;
    int lane = tid & 63, w = tid >> 6;
    int wr = w >> 1, wc = w & 1;
    int quad = lane >> 4, l16 = lane & 15;
    int sr = lane >> 2, sc = lane & 3;

    const short* aptr[2];
    #pragma unroll
    for (int i = 0; i < 2; i++) {
        int row = w * 32 + i * 16 + sr;
        int mrow = m0 + row;
        int cl = mrow < Mrows ? mrow : (Mrows - 1);
        size_t arow = routed ? (size_t)row_token[rowbase + cl] : (size_t)cl;
        aptr[i] = xb + arow * K + sc * 8;
    }

    int nb = tid & 63, kg = tid >> 6;
    const float* b1g = B1 + (size_t)(kg * 8) * N + n0 + nb;
    const float* b2g = B2 + (size_t)(kg * 8) * N + n0 + nb;
    const int bwr = nb * 32 + ((kg * 8) ^ ((nb & 3) << 3));

    f32x4 acc1[4][2] = {};
    f32x4 acc2[4][2] = {};

    const int nk = K >> 5;                 // 32
    auto stageA = [&](int slot) {
        #pragma unroll
        for (int i = 0; i < 2; i++) {
            gl2lds16(aptr[i], &As[slot * 4096 + (w * 32 + i * 16) * 32]);
            aptr[i] += 32;
        }
    };
    auto loadB = [&](float (&fb)[2][8]) {
        #pragma unroll
        for (int jj = 0; jj < 8; jj++) fb[0][jj] = b1g[(size_t)jj * N];
        #pragma unroll
        for (int jj = 0; jj < 8; jj++) fb[1][jj] = b2g[(size_t)jj * N];
        b1g += (size_t)32 * N;
        b2g += (size_t)32 * N;
    };
    auto writeB = [&](int buf, float (&fb)[2][8]) {
        uint32_t w0[4], w1[4];
        #pragma unroll
        for (int q = 0; q < 4; q++) {
            w0[q] = cvtpk(fb[0][2 * q], fb[0][2 * q + 1]);
            w1[q] = cvtpk(fb[1][2 * q], fb[1][2 * q + 1]);
        }
        *(uint4*)&Bs1[buf * 2048 + bwr] = *(uint4*)w0;
        *(uint4*)&Bs2[buf * 2048 + bwr] = *(uint4*)w1;
    };

    float fbA[2][8], fbB[2][8];
    stageA(0);
    stageA(1);
    __builtin_amdgcn_sched_barrier(0);
    {
        float fb0[2][8];
        loadB(fb0);
        writeB(0, fb0);                    // implicit wait drains fb0 (+A0,A1)
    }
    __builtin_amdgcn_sched_barrier(0);
    loadB(fbA);                            // tile 1, left in flight
    asm volatile("s_waitcnt vmcnt(16) lgkmcnt(0)" ::: "memory");
    __builtin_amdgcn_s_barrier();
    __builtin_amdgcn_sched_barrier(0);

    auto kstep = [&](int t, float (&fbIn)[2][8], float (&fbOut)[2][8]) {
        int slot = t % 3;
        int bbuf = t & 1;
        bool pf = (t + 2 < nk);
        if (pf) { stageA((t + 2) % 3); loadB(fbOut); }

        short8 a[4], b1[2], b2[2];
        #pragma unroll
        for (int i = 0; i < 4; i++)
            a[i] = *(const short8*)&As[slot * 4096 + (wr * 64 + i * 16 + l16) * 32 + quad * 8];
        #pragma unroll
        for (int j = 0; j < 2; j++) {
            int row = wc * 32 + j * 16 + l16;
            int ro = row * 32 + ((quad * 8) ^ ((row & 3) << 3));
            b1[j] = *(const short8*)&Bs1[bbuf * 2048 + ro];
            b2[j] = *(const short8*)&Bs2[bbuf * 2048 + ro];
        }
        #pragma unroll
        for (int i = 0; i < 4; i++)
            #pragma unroll
            for (int j = 0; j < 2; j++) {
                acc1[i][j] = __builtin_amdgcn_mfma_f32_16x16x32_bf16(a[i], b1[j], acc1[i][j], 0, 0, 0);
                acc2[i][j] = __builtin_amdgcn_mfma_f32_16x16x32_bf16(a[i], b2[j], acc2[i][j], 0, 0, 0);
            }
        if (t + 1 < nk) {
            writeB((t + 1) & 1, fbIn);     // implicit wait on fbIn (drains A(t+1))
            if (pf) asm volatile("s_waitcnt vmcnt(18) lgkmcnt(0)" ::: "memory");
            else    asm volatile("s_waitcnt vmcnt(0) lgkmcnt(0)" ::: "memory");
            __builtin_amdgcn_s_barrier();
            __builtin_amdgcn_sched_barrier(0);
        }
    };

    for (int t = 0; t < nk; t += 2) {
        kstep(t, fbA, fbB);
        if (t + 1 < nk) kstep(t + 1, fbB, fbA);
    }

    #pragma unroll
    for (int i = 0; i < 4; i++) {
        #pragma unroll
        for (int rr = 0; rr < 4; rr++) {
            int row = m0 + wr * 64 + i * 16 + quad * 4 + rr;
            if (row >= Mrows) continue;
            size_t orow = (size_t)(rowbase + row);
            #pragma unroll
            for (int j = 0; j < 2; j++) {
                int n = n0 + wc * 32 + j * 16 + l16;
                float v = acc1[i][j][rr];
                float u = acc2[i][j][rr];
                float h = v / (1.f + __expf(-v)) * u;
                Cout[orow * N + n] = f2bf(h);
            }
        }
    }
}

// ---------------- unified DOWN GEMM: fp32-direct B (R18-exact), shared-heavy first
__global__ __launch_bounds__(256, 3)
void down_all_k(const short* __restrict__ Hr, const short* __restrict__ Hs,
                const float* __restrict__ down_w, const float* __restrict__ shd_w,
                float* __restrict__ O, float* __restrict__ out,
                const int* __restrict__ counts, const int* __restrict__ base,
                const float* __restrict__ row_wgt,
                const int* __restrict__ tile_e, const int* __restrict__ tile_m0) {
    constexpr int N = C_DIM;

    int bid = blockIdx.x;
    bool shared_e = bid < NB_SHARED_D;     // heavy blocks first (4x work)
    const short* A; const float* B1; float* Cout;
    int m0, n0, Mrows, rowbase, K;
    if (shared_e) {
        m0 = (bid >> 3) * 128; n0 = (bid & 7) * 128;
        Mrows = S_TOK; rowbase = 0;
        K = HS_DIM;
        A = Hs;
        B1 = shd_w;
        Cout = out;
    } else {
        int rb = bid - NB_SHARED_D;
        int ti = rb >> 3;
        int e = tile_e[ti];
        if (e < 0) return;
        m0 = tile_m0[ti]; n0 = (rb & 7) * 128;
        Mrows = counts[e]; rowbase = base[e];
        K = H_DIM;
        A = Hr;
        B1 = down_w + (size_t)e * H_DIM * N;
        Cout = O;
    }

    __shared__ short As[3 * 4096];        // 24 KB
    __shared__ short Bs1[2 * 4096];       // 16 KB -> 40 KB, 3 blocks/CU

    int tid = threadIdx.x;
    int lane = tid & 63, w = tid >> 6;
    int wr = w >> 1, wc = w & 1;
    int quad = lane >> 4, l16 = lane & 15;
    int sr = lane >> 2, sc = lane & 3;

    const short* aptr[2];
    #pragma unroll
    for (int i = 0; i < 2; i++) {
        int row = w * 32 + i * 16 + sr;
        int mrow = m0 + row;
        int cl = mrow < Mrows ? mrow : (Mrows - 1);
        aptr[i] = A + (size_t)(rowbase + cl) * K + sc * 8;
    }

    int nb = tid & 63, kg = tid >> 6;
    const float* b1g = B1 + (size_t)(kg * 8) * N + n0 + nb;
    const int bwr = nb * 32 + ((kg * 8) ^ ((nb & 3) << 3));

    f32x4 acc1[4][4] = {};

    const int nk = K >> 5;                 // 16 or 64
    auto stageA = [&](int slot) {
        #pragma unroll
        for (int i = 0; i < 2; i++) {
            gl2lds16(aptr[i], &As[slot * 4096 + (w * 32 + i * 16) * 32]);
            aptr[i] += 32;
        }
    };
    auto loadB = [&](float (&fb)[2][8]) {
        #pragma unroll
        for (int jj = 0; jj < 8; jj++) fb[0][jj] = b1g[(size_t)jj * N];
        #pragma unroll
        for (int jj = 0; jj < 8; jj++) fb[1][jj] = b1g[(size_t)jj * N + 64];
        b1g += (size_t)32 * N;
    };
    auto writeB = [&](int buf, float (&fb)[2][8]) {
        uint32_t w0[4], w1[4];
        #pragma unroll
        for (int q = 0; q < 4; q++) {
            w0[q] = cvtpk(fb[0][2 * q], fb[0][2 * q + 1]);
            w1[q] = cvtpk(fb[1][2 * q], fb[1][2 * q + 1]);
        }
        *(uint4*)&Bs1[buf * 4096 + bwr] = *(uint4*)w0;
        *(uint4*)&Bs1[buf * 4096 + bwr + 64 * 32] = *(uint4*)w1;
    };

    float fbA[2][8], fbB[2][8];
    stageA(0);
    stageA(1);
    __builtin_amdgcn_sched_barrier(0);
    {
        float fb0[2][8];
        loadB(fb0);
        writeB(0, fb0);
    }
    __builtin_amdgcn_sched_barrier(0);
    loadB(fbA);
    asm volatile("s_waitcnt vmcnt(16) lgkmcnt(0)" ::: "memory");
    __builtin_amdgcn_s_barrier();
    __builtin_amdgcn_sched_barrier(0);

    auto kstep = [&](int t, float (&fbIn)[2][8], float (&fbOut)[2][8]) {
        int slot = t % 3;
        int bbuf = t & 1;
        bool pf = (t + 2 < nk);
        if (pf) { stageA((t + 2) % 3); loadB(fbOut); }

        short8 a[4], b1[4];
        #pragma unroll
        for (int i = 0; i < 4; i++)
            a[i] = *(const short8*)&As[slot * 4096 + (wr * 64 + i * 16 + l16) * 32 + quad * 8];
        #pragma unroll
        for (int j = 0; j < 4; j++) {
            int row = wc * 64 + j * 16 + l16;
            int ro = row * 32 + ((quad * 8) ^ ((row & 3) << 3));
            b1[j] = *(const short8*)&Bs1[bbuf * 4096 + ro];
        }
        #pragma unroll
        for (int i = 0; i < 4; i++)
            #pragma unroll
            for (int j = 0; j < 4; j++)
                acc1[i][j] = __builtin_amdgcn_mfma_f32_16x16x32_bf16(a[i], b1[j], acc1[i][j], 0, 0, 0);
        if (t + 1 < nk) {
            writeB((t + 1) & 1, fbIn);
            if (pf) asm volatile("s_waitcnt vmcnt(18) lgkmcnt(0)" ::: "memory");
            else    asm volatile("s_waitcnt vmcnt(0) lgkmcnt(0)" ::: "memory");
            __builtin_amdgcn_s_barrier();
            __builtin_amdgcn_sched_barrier(0);
        }
    };

    for (int t = 0; t < nk; t += 2) {
        kstep(t, fbA, fbB);
        if (t + 1 < nk) kstep(t + 1, fbB, fbA);
    }

    #pragma unroll
    for (int i = 0; i < 4; i++) {
        #pragma unroll
        for (int rr = 0; rr < 4; rr++) {
            int row = m0 + wr * 64 + i * 16 + quad * 4 + rr;
            if (row >= Mrows) continue;
            size_t orow = (size_t)(rowbase + row);
            float scl = shared_e ? 1.f : row_wgt[rowbase + row];
            #pragma unroll
            for (int j = 0; j < 4; j++) {
                int n = n0 + wc * 64 + j * 16 + l16;
                Cout[orow * N + n] = acc1[i][j][rr] * scl;
            }
        }
    }
}

// ---------------- launch ----------------
extern "C" void kernel_launch(void* const* d_in, const int* in_sizes, int n_in,
                              void* d_out, int out_size, void* d_ws, size_t ws_size,
                              hipStream_t stream) {
    const float* x        = (const float*)d_in[0];
    const float* router_w = (const float*)d_in[1];
    const float* e_bias   = (const float*)d_in[2];
    const float* gate_w   = (const float*)d_in[3];
    const float* up_w     = (const float*)d_in[4];
    const float* down_w   = (const float*)d_in[5];
    const float* sh_gate  = (const float*)d_in[6];
    const float* sh_up    = (const float*)d_in[7];
    const float* sh_down  = (const float*)d_in[8];
    float* out = (float*)d_out;
    char* ws = (char*)d_ws;

    int*   counts    = (int*)(ws);
    int*   base      = (int*)(ws + 256);
    int*   cursor    = (int*)(ws + 512);
    int*   done      = (int*)(ws + 768);
    int*   flag      = (int*)(ws + 772);
    int*   topk_idx  = (int*)(ws + 1024);
    float* topk_w    = (float*)(ws + 1024 + 131072);
    int*   row_token = (int*)(ws + 1024 + 2 * 131072);
    float* row_wgt   = (float*)(ws + 1024 + 3 * 131072);
    int*   pos_of    = (int*)(ws + 1664 * 1024);                   // 128 KB
    int*   tile_e    = (int*)(ws + 1800 * 1024);
    int*   tile_m0   = (int*)(ws + 1808 * 1024);
    const size_t MB = 1u << 20;
    unsigned short* xb = (unsigned short*)(ws + 2 * MB);           // 8 MB
    unsigned short* Hs = (unsigned short*)(ws + 10 * MB);          // 16 MB
    unsigned short* Hr = (unsigned short*)(ws + 26 * MB);          // 32 MB
    float*          O  = (float*)(ws + 70 * MB);                   // 128 MB

    // zero counts/base/cursor/done/flag (graph-capturable)
    hipMemsetAsync(ws, 0, 1024, stream);

    // ---- routing chain: scores + topk + scan + xcvt + scatter, one dispatch ----
    router_all_k<<<S_TOK / 32, 256, 0, stream>>>(
        x, router_w, e_bias, topk_idx, topk_w, counts, done, flag,
        base, cursor, tile_e, tile_m0, row_token, row_wgt, pos_of, xb);

    // ---- unified fused gate+up (routed + shared), fp32-direct weights ----
    fused_all_k<<<NB_ROUTED_F + NB_SHARED_F, 256, 0, stream>>>(
        (const short*)xb, gate_w, up_w, sh_gate, sh_up, Hr, Hs,
        counts, base, row_token, tile_e, tile_m0);

    // ---- unified down (shared heavy first), fp32-direct weights ----
    down_all_k<<<NB_SHARED_D + NB_ROUTED_D, 256, 0, stream>>>(
        (const short*)Hr, (const short*)Hs, down_w, sh_down,
        O, out, counts, base, row_wgt, tile_e, tile_m0);

    // ---- combine routed into out (out already holds shared-expert result) ----
    combine_k<<<S_TOK, 256, 0, stream>>>(O, pos_of, out);
}